// Round 8
// baseline (409.931 us; speedup 1.0000x reference)
//
#include <hip/hip_runtime.h>

typedef unsigned short u16;
typedef __attribute__((ext_vector_type(8))) short bf16x8;
typedef __attribute__((ext_vector_type(4))) float f32x4;
typedef __attribute__((ext_vector_type(4))) unsigned short us4;
typedef __attribute__((ext_vector_type(8))) unsigned short us8;

#define S_LEN 2048
#define QKV_P 6144
#define WIN_SZ 1024
#define SCALE_F 0.08838834764831845f
#define LAMBDA_INIT_F 0.35550906759096925f
#define ONE_MINUS_LI_F 0.6444909324090308f

__device__ __forceinline__ u16 f2bf(float f) {
    union { float f; unsigned int u; } v; v.f = f;
    unsigned int u = v.u;
    return (u16)((u + 0x7fffu + ((u >> 16) & 1u)) >> 16);
}
__device__ __forceinline__ float bf2f(u16 u) {
    union { unsigned int u; float f; } v; v.u = ((unsigned int)u) << 16; return v.f;
}
__device__ __forceinline__ void gload16(const void* g, void* l) {
    __builtin_amdgcn_global_load_lds(
        (const __attribute__((address_space(1))) unsigned int*)g,
        (__attribute__((address_space(3))) unsigned int*)l, 16, 0, 0);
}

// ---------------------------------------------------------------------------
// f32 -> bf16 elementwise convert
// ---------------------------------------------------------------------------
__global__ __launch_bounds__(256)
void conv_f32_bf16(const float* __restrict__ src, u16* __restrict__ dst, int n4) {
    for (int i = blockIdx.x * 256 + threadIdx.x; i < n4; i += gridDim.x * 256) {
        float4 v = ((const float4*)src)[i];
        us4 h;
        h.x = f2bf(v.x); h.y = f2bf(v.y); h.z = f2bf(v.z); h.w = f2bf(v.w);
        ((us4*)dst)[i] = h;
    }
}

// ---------------------------------------------------------------------------
// 8-phase 256xBN GEMM, BN = NF*64.  512 thr = 8 waves (2M x 4N).
// ---------------------------------------------------------------------------
template<int NR>
__device__ __forceinline__ void stage_half(const u16* __restrict__ src, int K,
                                           int gRowBase, int kcol0,
                                           u16* slot, int tid, int wid) {
#pragma unroll
    for (int g = 0; g < 2; ++g) {
        if (g * 128 + wid * 16 < NR) {   // wave-uniform
            int row = g * 128 + (tid >> 2);
            int cc = (tid & 3) ^ ((row >> 1) & 3);
            gload16(src + (size_t)(gRowBase + row) * K + kcol0 + cc * 8,
                    slot + g * 4096 + wid * 512);
        }
    }
}

__device__ __forceinline__ bf16x8 ldfrag(const u16* slot, int row, int l4) {
    int pc = l4 ^ ((row >> 1) & 3);
    return *(const bf16x8*)(slot + row * 32 + pc * 8);
}

template<int NF>
__device__ __forceinline__ void gemm_wait(int wid) {
    if constexpr (NF == 3) {
        if (wid < 4) asm volatile("s_waitcnt vmcnt(4)" ::: "memory");
        else         asm volatile("s_waitcnt vmcnt(3)" ::: "memory");
    } else if constexpr (NF == 2) {
        asm volatile("s_waitcnt vmcnt(3)" ::: "memory");
    } else {
        asm volatile("s_waitcnt vmcnt(4)" ::: "memory");
    }
}

template<int NF, int OUT_BF16>
__global__ __launch_bounds__(512, 2)
void gemm8p(const u16* __restrict__ A, const u16* __restrict__ W,
            const float* __restrict__ bias, void* __restrict__ Cv,
            int M, int N, int K, int nbx) {
    constexpr int BN = NF * 64;
    constexpr int BSLOT = NF * 2048;            // u16 per B slot
    __shared__ u16 lds[32768 + 4 * BSLOT];

    const int tid = threadIdx.x;
    const int wid = tid >> 6, lane = tid & 63;
    const int wr = wid >> 2, wc = wid & 3;
    const int l15 = lane & 15, l4 = lane >> 4;

    const int nwg = gridDim.x;
    const int q8 = nwg >> 3;
    const int swz = (blockIdx.x & 7) * q8 + (blockIdx.x >> 3);
    const int bx = swz % nbx, by = swz / nbx;
    const int rowBase = by * 256;
    const int colBase = bx * BN;

    const int NT = K >> 6;

    u16* const baseA = lds;
    u16* const baseB = lds + 32768;

    f32x4 acc[8][NF] = {};

    stage_half<256>(A, K, rowBase, 0,  baseA + 0 * 8192, tid, wid);
    stage_half<BN> (W, K, colBase, 0,  baseB + 0 * BSLOT, tid, wid);
    stage_half<256>(A, K, rowBase, 32, baseA + 1 * 8192, tid, wid);
    stage_half<BN> (W, K, colBase, 32, baseB + 1 * BSLOT, tid, wid);
    stage_half<256>(A, K, rowBase, 64, baseA + 2 * 8192, tid, wid);
    stage_half<BN> (W, K, colBase, 64, baseB + 2 * BSLOT, tid, wid);
    gemm_wait<NF>(wid);
    __builtin_amdgcn_s_barrier();

    for (int t = 0; t < NT; ++t) {
        const int b = t & 1;
        const int bn = b ^ 1;
        u16* const A0 = baseA + (b * 2 + 0) * 8192;
        u16* const A1 = baseA + (b * 2 + 1) * 8192;
        u16* const B0 = baseB + (b * 2 + 0) * BSLOT;
        u16* const B1 = baseB + (b * 2 + 1) * BSLOT;

        bf16x8 af[4], bfv[NF];

        // phase 0: kk0, m0-3
#pragma unroll
        for (int m = 0; m < 4; ++m) af[m] = ldfrag(A0, wr * 128 + m * 16 + l15, l4);
#pragma unroll
        for (int n = 0; n < NF; ++n) bfv[n] = ldfrag(B0, wc * (NF * 16) + n * 16 + l15, l4);
        if (t + 1 < NT)
            stage_half<256>(A, K, rowBase, (t + 1) * 64 + 32, baseA + (bn * 2 + 1) * 8192, tid, wid);
        __builtin_amdgcn_s_barrier();
        __builtin_amdgcn_s_setprio(1);
#pragma unroll
        for (int m = 0; m < 4; ++m)
#pragma unroll
            for (int n = 0; n < NF; ++n)
                acc[m][n] = __builtin_amdgcn_mfma_f32_16x16x32_bf16(af[m], bfv[n], acc[m][n], 0, 0, 0);
        __builtin_amdgcn_s_setprio(0);
        __builtin_amdgcn_s_barrier();

        // phase 1: kk0, m4-7
#pragma unroll
        for (int m = 0; m < 4; ++m) af[m] = ldfrag(A0, wr * 128 + (m + 4) * 16 + l15, l4);
        if (t + 1 < NT)
            stage_half<BN>(W, K, colBase, (t + 1) * 64 + 32, baseB + (bn * 2 + 1) * BSLOT, tid, wid);
        __builtin_amdgcn_s_barrier();
        __builtin_amdgcn_s_setprio(1);
#pragma unroll
        for (int m = 0; m < 4; ++m)
#pragma unroll
            for (int n = 0; n < NF; ++n)
                acc[m + 4][n] = __builtin_amdgcn_mfma_f32_16x16x32_bf16(af[m], bfv[n], acc[m + 4][n], 0, 0, 0);
        __builtin_amdgcn_s_setprio(0);
        __builtin_amdgcn_s_barrier();

        // phase 2: kk1, m0-3
#pragma unroll
        for (int m = 0; m < 4; ++m) af[m] = ldfrag(A1, wr * 128 + m * 16 + l15, l4);
#pragma unroll
        for (int n = 0; n < NF; ++n) bfv[n] = ldfrag(B1, wc * (NF * 16) + n * 16 + l15, l4);
        if (t + 2 < NT)
            stage_half<256>(A, K, rowBase, (t + 2) * 64, baseA + (b * 2 + 0) * 8192, tid, wid);
        __builtin_amdgcn_s_barrier();
        __builtin_amdgcn_s_setprio(1);
#pragma unroll
        for (int m = 0; m < 4; ++m)
#pragma unroll
            for (int n = 0; n < NF; ++n)
                acc[m][n] = __builtin_amdgcn_mfma_f32_16x16x32_bf16(af[m], bfv[n], acc[m][n], 0, 0, 0);
        __builtin_amdgcn_s_setprio(0);
        __builtin_amdgcn_s_barrier();

        // phase 3: kk1, m4-7
#pragma unroll
        for (int m = 0; m < 4; ++m) af[m] = ldfrag(A1, wr * 128 + (m + 4) * 16 + l15, l4);
        if (t + 2 < NT)
            stage_half<BN>(W, K, colBase, (t + 2) * 64, baseB + (b * 2 + 0) * BSLOT, tid, wid);
        __builtin_amdgcn_s_barrier();
        __builtin_amdgcn_s_setprio(1);
#pragma unroll
        for (int m = 0; m < 4; ++m)
#pragma unroll
            for (int n = 0; n < NF; ++n)
                acc[m + 4][n] = __builtin_amdgcn_mfma_f32_16x16x32_bf16(af[m], bfv[n], acc[m + 4][n], 0, 0, 0);
        __builtin_amdgcn_s_setprio(0);
        if (t + 2 < NT) gemm_wait<NF>(wid);
        else            asm volatile("s_waitcnt vmcnt(0)" ::: "memory");
        __builtin_amdgcn_s_barrier();
    }

#pragma unroll
    for (int n = 0; n < NF; ++n) {
        int col = colBase + wc * (NF * 16) + n * 16 + l15;
        float bs = bias[col];
#pragma unroll
        for (int m = 0; m < 8; ++m)
#pragma unroll
            for (int rr = 0; rr < 4; ++rr) {
                int rowi = rowBase + wr * 128 + m * 16 + l4 * 4 + rr;
                float v = acc[m][n][rr] + bs;
                if (OUT_BF16) ((u16*)Cv)[(size_t)rowi * N + col] = f2bf(v);
                else          ((float*)Cv)[(size_t)rowi * N + col] = v;
            }
    }
}

// ---------------------------------------------------------------------------
// RoPE in-place on bf16 qkv.
// ---------------------------------------------------------------------------
__global__ __launch_bounds__(256)
void rope_bf16(u16* __restrict__ qkv, const int* __restrict__ positions) {
    const int row = blockIdx.x;
    const float pos = (float)positions[row];
    for (int idx = threadIdx.x; idx < 640; idx += 256) {
        int head = idx >> 4;
        int g = idx & 15;
        int base = (head < 32) ? head * 128 : 4096 + (head - 32) * 128;
        u16* p = qkv + (size_t)row * QKV_P + base + g * 4;
        us4 x1 = *(us4*)p;
        us4 x2 = *(us4*)(p + 64);
#pragma unroll
        for (int j = 0; j < 4; ++j) {
            float inv_freq = __expf(-(float)(g * 4 + j) * (9.210340371976184f / 64.0f));
            float ang = pos * inv_freq;
            float s, c;
            sincosf(ang, &s, &c);
            float a = bf2f(x1[j]), b = bf2f(x2[j]);
            x1[j] = f2bf(a * c - b * s);
            x2[j] = f2bf(b * c + a * s);
        }
        *(us4*)p = x1;
        *(us4*)(p + 64) = x2;
    }
}

// ---------------------------------------------------------------------------
// V transpose: qkv V-region -> vt[a][d][s].
// ---------------------------------------------------------------------------
__global__ __launch_bounds__(256)
void vtrans(const u16* __restrict__ qkv, u16* __restrict__ vt) {
    __shared__ u16 T[128 * 72];
    const int s0 = blockIdx.x * 64;
    const int a = blockIdx.y;
    const u16* src = qkv + 5120 + a * 128;
#pragma unroll
    for (int it = 0; it < 4; ++it) {
        int idx = it * 256 + threadIdx.x;
        int s = idx >> 4;
        int c8 = idx & 15;
        us8 v = *(const us8*)(src + (size_t)(s0 + s) * QKV_P + c8 * 8);
        int sc = s >> 3, su = s & 7;
#pragma unroll
        for (int j = 0; j < 8; ++j) {
            int d = c8 * 8 + j;
            T[d * 72 + ((sc ^ ((d >> 3) & 7)) * 8 + su)] = v[j];
        }
    }
    __syncthreads();
#pragma unroll
    for (int it = 0; it < 4; ++it) {
        int idx = it * 256 + threadIdx.x;
        int d = idx >> 3, sc = idx & 7;
        us8 v = *(const us8*)&T[d * 72 + ((sc ^ ((d >> 3) & 7)) * 8)];
        *(us8*)(vt + (size_t)a * 262144 + (size_t)d * 2048 + s0 + sc * 8) = v;
    }
}

// ---------------------------------------------------------------------------
// Dual-stream sliding-window flash attention + fused RMS-norm.
// 256 blocks (128 q-rows x half-head-pair), 8 waves. K/V double-buffered
// (stage t+1 at tile top, ONE vmcnt(0)+barrier per tile). P per-wave private.
// LDS 144 KB -> 1 block/CU. launch_bounds(512,2): VGPR cap 256 (NOT the
// default 128 -- the acc set is ~230 regs; a 128 cap spills it to scratch,
// +25MB HBM writes/pass, measured rounds 5 & 7).
// ---------------------------------------------------------------------------
__global__ __launch_bounds__(512, 2)
void attn_bf16(const u16* __restrict__ qkv, const u16* __restrict__ vtg,
               u16* __restrict__ attnb,
               const float* __restrict__ lq1, const float* __restrict__ lk1,
               const float* __restrict__ lq2, const float* __restrict__ lk2,
               const float* __restrict__ subln) {
    __shared__ u16 Kb[2][2][64 * 128];   // [buf][stream] 64 KB
    __shared__ u16 Vb[2][2][128 * 64];   // [buf][stream] 64 KB
    __shared__ u16 Pw[8][16 * 64];       // per-wave P, 16 KB

    const int tid = threadIdx.x;
    const int w = tid >> 6, lane = tid & 63;
    const int l15 = lane & 15, l4 = lane >> 4;

    const int qb = blockIdx.x & 15;
    const int h  = blockIdx.x >> 4;
    const int q0 = qb * 128;
    const int h1 = 2 * h, h2 = 2 * h + 1;
    const int a1 = 2 * (h >> 2), a2 = a1 + 1;

    // Q fragments: wave w owns q-rows q0 + w*16 .. +15
    bf16x8 q1f[4], q2f[4];
    {
        int qrow = q0 + w * 16 + l15;
        const u16* qp1 = qkv + (size_t)qrow * QKV_P + h1 * 128;
        const u16* qp2 = qkv + (size_t)qrow * QKV_P + h2 * 128;
#pragma unroll
        for (int kk = 0; kk < 4; ++kk) {
            q1f[kk] = *(const bf16x8*)(qp1 + kk * 32 + l4 * 8);
            q2f[kk] = *(const bf16x8*)(qp2 + kk * 32 + l4 * 8);
        }
    }

    f32x4 a11[8] = {}, a12[8] = {}, a21[8] = {}, a22[8] = {};
    float m1[4], l1[4], m2[4], l2[4];
#pragma unroll
    for (int r = 0; r < 4; ++r) { m1[r] = -1e30f; l1[r] = 0.f; m2[r] = -1e30f; l2[r] = 0.f; }

    const int kr4 = lane >> 4;   // K stage: row within 4-row chunk
    const int kc  = lane & 15;
    const int vd8 = lane >> 3;   // V stage: d-row within 8-row chunk
    const int vc  = lane & 7;

    const int tbeg = (qb >= 8) ? ((q0 - (WIN_SZ - 1)) >> 6) : 0;
    const int tend = (q0 + 127) >> 6;

#define STAGE_TILE(T, NB)                                                      \
    {                                                                          \
        const int kv0s = (T) * 64;                                             \
        _Pragma("unroll")                                                      \
        for (int s = 0; s < 2; ++s) {                                          \
            int ch = w * 2 + s;                                                \
            int krow = ch * 4 + kr4;                                           \
            int kcs = (kc ^ (krow & 7)) * 8;                                   \
            const u16* kbase = qkv + (size_t)(kv0s + krow) * QKV_P + 4096;     \
            gload16(kbase + a1 * 128 + kcs, &Kb[NB][0][ch * 512]);             \
            gload16(kbase + a2 * 128 + kcs, &Kb[NB][1][ch * 512]);             \
            int vdrow = ch * 8 + vd8;                                          \
            int vcs = (vc ^ (vdrow & 7)) * 8;                                  \
            const u16* vbase = vtg + (size_t)vdrow * 2048 + kv0s + vcs;        \
            gload16(vbase + (size_t)a1 * 262144, &Vb[NB][0][ch * 512]);        \
            gload16(vbase + (size_t)a2 * 262144, &Vb[NB][1][ch * 512]);        \
        }                                                                      \
    }

    // prologue
    STAGE_TILE(tbeg, 0);
    asm volatile("s_waitcnt vmcnt(0)" ::: "memory");
    __builtin_amdgcn_s_barrier();
    asm volatile("" ::: "memory");

    int cb = 0;
    for (int t = tbeg; t <= tend; ++t) {
        const int kv0 = t * 64;

        // issue next tile's stage first (latency hides under whole tile)
        if (t < tend) STAGE_TILE(t + 1, cb ^ 1);

        // --- QK^T from buf cb
        f32x4 sc1[4], sc2[4];
        __builtin_amdgcn_s_setprio(1);
#pragma unroll
        for (int c = 0; c < 4; ++c) {
            f32x4 s1 = {0.f, 0.f, 0.f, 0.f};
            f32x4 s2 = {0.f, 0.f, 0.f, 0.f};
#pragma unroll
            for (int kk = 0; kk < 4; ++kk) {
                int off = (c * 16 + l15) * 128 + (((kk * 4 + l4) ^ (l15 & 7)) * 8);
                bf16x8 kf1 = *(const bf16x8*)&Kb[cb][0][off];
                bf16x8 kf2 = *(const bf16x8*)&Kb[cb][1][off];
                s1 = __builtin_amdgcn_mfma_f32_16x16x32_bf16(q1f[kk], kf1, s1, 0, 0, 0);
                s2 = __builtin_amdgcn_mfma_f32_16x16x32_bf16(q2f[kk], kf2, s2, 0, 0, 0);
            }
            sc1[c] = s1; sc2[c] = s2;
        }
        __builtin_amdgcn_s_setprio(0);

        // --- masks: causal zone (last 2 tiles), window zone (first 2, qb>=8)
        const bool dz = (t >= tend - 1);
        const bool wz = (qb >= 8) && (t <= tbeg + 1);
        if (dz) {
#pragma unroll
            for (int c = 0; c < 4; ++c) {
                int j = kv0 + c * 16 + l15;
#pragma unroll
                for (int r = 0; r < 4; ++r) {
                    int i = q0 + w * 16 + l4 * 4 + r;
                    if (j > i) { sc1[c][r] = -1e30f; sc2[c][r] = -1e30f; }
                }
            }
        } else if (wz) {
#pragma unroll
            for (int c = 0; c < 4; ++c) {
                int j = kv0 + c * 16 + l15;
#pragma unroll
                for (int r = 0; r < 4; ++r) {
                    int i = q0 + w * 16 + l4 * 4 + r;
                    if (i - j >= WIN_SZ) { sc1[c][r] = -1e30f; sc2[c][r] = -1e30f; }
                }
            }
        }

        // --- row max + defer-max rescale
        float rmax1[4], rmax2[4];
#pragma unroll
        for (int r = 0; r < 4; ++r) {
            rmax1[r] = fmaxf(fmaxf(sc1[0][r], sc1[1][r]), fmaxf(sc1[2][r], sc1[3][r]));
            rmax2[r] = fmaxf(fmaxf(sc2[0][r], sc2[1][r]), fmaxf(sc2[2][r], sc2[3][r]));
        }
#pragma unroll
        for (int msk = 1; msk < 16; msk <<= 1)
#pragma unroll
            for (int r = 0; r < 4; ++r) {
                rmax1[r] = fmaxf(rmax1[r], __shfl_xor(rmax1[r], msk));
                rmax2[r] = fmaxf(rmax2[r], __shfl_xor(rmax2[r], msk));
            }
        bool need = false;
#pragma unroll
        for (int r = 0; r < 4; ++r)
            need = need || (rmax1[r] > m1[r] + 32.0f) || (rmax2[r] > m2[r] + 32.0f);
        if (__any(need)) {
            float f1[4], f2[4];
#pragma unroll
            for (int r = 0; r < 4; ++r) {
                float nm1 = fmaxf(m1[r], rmax1[r]);
                float nm2 = fmaxf(m2[r], rmax2[r]);
                f1[r] = __expf((m1[r] - nm1) * SCALE_F);
                f2[r] = __expf((m2[r] - nm2) * SCALE_F);
                m1[r] = nm1; m2[r] = nm2;
                l1[r] *= f1[r]; l2[r] *= f2[r];
            }
#pragma unroll
            for (int f = 0; f < 8; ++f)
#pragma unroll
                for (int r = 0; r < 4; ++r) {
                    a11[f][r] *= f1[r]; a12[f][r] *= f1[r];
                    a21[f][r] *= f2[r]; a22[f][r] *= f2[r];
                }
        }

        // --- P = exp((s-m)*SCALE); rowsum; stream-1 P to LDS (wave-private)
        float rs1[4] = {0.f, 0.f, 0.f, 0.f}, rs2[4] = {0.f, 0.f, 0.f, 0.f};
#pragma unroll
        for (int c = 0; c < 4; ++c) {
            int col = c * 16 + l15;
#pragma unroll
            for (int r = 0; r < 4; ++r) {
                int prow = l4 * 4 + r;
                float p1 = __expf((sc1[c][r] - m1[r]) * SCALE_F);
                float p2 = __expf((sc2[c][r] - m2[r]) * SCALE_F);
                if (wz) {
                    if (m1[r] < -1e29f) p1 = 0.f;
                    if (m2[r] < -1e29f) p2 = 0.f;
                }
                rs1[r] += p1; rs2[r] += p2;
                sc2[c][r] = p2;   // keep stream-2 P in regs for after PV1
                int pco = ((col >> 3) ^ (prow & 7)) * 8 + (col & 7);
                Pw[w][prow * 64 + pco] = f2bf(p1);
            }
        }
#pragma unroll
        for (int msk = 1; msk < 16; msk <<= 1)
#pragma unroll
            for (int r = 0; r < 4; ++r) {
                rs1[r] += __shfl_xor(rs1[r], msk);
                rs2[r] += __shfl_xor(rs2[r], msk);
            }
#pragma unroll
        for (int r = 0; r < 4; ++r) { l1[r] += rs1[r]; l2[r] += rs2[r]; }

        // --- PV stream 1 (a11 += P1*V1, a12 += P1*V2)
        __builtin_amdgcn_s_setprio(1);
#pragma unroll
        for (int kk = 0; kk < 2; ++kk) {
            int pch = ((kk * 4 + l4) ^ (l15 & 7)) * 8;
            bf16x8 pa = *(const bf16x8*)&Pw[w][l15 * 64 + pch];
#pragma unroll
            for (int f = 0; f < 8; ++f) {
                int off = (f * 16 + l15) * 64 + (((kk * 4 + l4) ^ (l15 & 7)) * 8);
                bf16x8 vb1 = *(const bf16x8*)&Vb[cb][0][off];
                bf16x8 vb2 = *(const bf16x8*)&Vb[cb][1][off];
                a11[f] = __builtin_amdgcn_mfma_f32_16x16x32_bf16(pa, vb1, a11[f], 0, 0, 0);
                a12[f] = __builtin_amdgcn_mfma_f32_16x16x32_bf16(pa, vb2, a12[f], 0, 0, 0);
            }
        }
        __builtin_amdgcn_s_setprio(0);

        // --- stream-2 P to LDS (same wave-private buffer), then PV stream 2
#pragma unroll
        for (int c = 0; c < 4; ++c) {
            int col = c * 16 + l15;
#pragma unroll
            for (int r = 0; r < 4; ++r) {
                int prow = l4 * 4 + r;
                int pco = ((col >> 3) ^ (prow & 7)) * 8 + (col & 7);
                Pw[w][prow * 64 + pco] = f2bf(sc2[c][r]);
            }
        }
        __builtin_amdgcn_s_setprio(1);
#pragma unroll
        for (int kk = 0; kk < 2; ++kk) {
            int pch = ((kk * 4 + l4) ^ (l15 & 7)) * 8;
            bf16x8 pa = *(const bf16x8*)&Pw[w][l15 * 64 + pch];
#pragma unroll
            for (int f = 0; f < 8; ++f) {
                int off = (f * 16 + l15) * 64 + (((kk * 4 + l4) ^ (l15 & 7)) * 8);
                bf16x8 vb1 = *(const bf16x8*)&Vb[cb][0][off];
                bf16x8 vb2 = *(const bf16x8*)&Vb[cb][1][off];
                a21[f] = __builtin_amdgcn_mfma_f32_16x16x32_bf16(pa, vb1, a21[f], 0, 0, 0);
                a22[f] = __builtin_amdgcn_mfma_f32_16x16x32_bf16(pa, vb2, a22[f], 0, 0, 0);
            }
        }
        __builtin_amdgcn_s_setprio(0);

        // --- single sync point: next tile staged + everyone done with buf cb
        asm volatile("s_waitcnt vmcnt(0)" ::: "memory");
        __builtin_amdgcn_s_barrier();
        asm volatile("" ::: "memory");
        cb ^= 1;
    }

    // lambda scalar
    float s1v = lq1[lane] * lk1[lane] + lq1[lane + 64] * lk1[lane + 64];
    float s2v = lq2[lane] * lk2[lane] + lq2[lane + 64] * lk2[lane + 64];
#pragma unroll
    for (int msk = 1; msk < 64; msk <<= 1) {
        s1v += __shfl_xor(s1v, msk);
        s2v += __shfl_xor(s2v, msk);
    }
    const float lam = __expf(s1v) - __expf(s2v) + LAMBDA_INIT_F;

    float sw0[8], sw1[8];
#pragma unroll
    for (int f = 0; f < 8; ++f) {
        sw0[f] = subln[f * 16 + l15];
        sw1[f] = subln[128 + f * 16 + l15];
    }

#pragma unroll
    for (int r = 0; r < 4; ++r) {
        float inv1 = 1.0f / l1[r];
        float inv2 = 1.0f / l2[r];
        float o0[8], o1[8];
        float ssq = 0.f;
#pragma unroll
        for (int f = 0; f < 8; ++f) {
            o0[f] = a11[f][r] * inv1 - lam * (a21[f][r] * inv2);
            o1[f] = a12[f][r] * inv1 - lam * (a22[f][r] * inv2);
            ssq += o0[f] * o0[f] + o1[f] * o1[f];
        }
#pragma unroll
        for (int msk = 1; msk < 16; msk <<= 1) ssq += __shfl_xor(ssq, msk);
        float scale = rsqrtf(ssq * (1.0f / 256.0f) + 1e-5f) * ONE_MINUS_LI_F;
        int row = q0 + w * 16 + l4 * 4 + r;
        u16* op = attnb + (size_t)row * 4096 + h * 256;
#pragma unroll
        for (int f = 0; f < 8; ++f) {
            op[f * 16 + l15]       = f2bf(o0[f] * scale * sw0[f]);
            op[128 + f * 16 + l15] = f2bf(o1[f] * scale * sw1[f]);
        }
    }
}

// ---------------------------------------------------------------------------
extern "C" void kernel_launch(void* const* d_in, const int* in_sizes, int n_in,
                              void* d_out, int out_size, void* d_ws, size_t ws_size,
                              hipStream_t stream) {
    const float* hidden    = (const float*)d_in[0];
    const int*   positions = (const int*)d_in[1];
    const float* Wqkv_w    = (const float*)d_in[2];
    const float* Wqkv_b    = (const float*)d_in[3];
    const float* out_w     = (const float*)d_in[4];
    const float* out_b     = (const float*)d_in[5];
    const float* lq1       = (const float*)d_in[6];
    const float* lk1       = (const float*)d_in[7];
    const float* lq2       = (const float*)d_in[8];
    const float* lk2       = (const float*)d_in[9];
    const float* subln     = (const float*)d_in[10];
    float* out = (float*)d_out;

    u16* ws0   = (u16*)d_ws;
    u16* hb    = ws0;
    u16* wqb   = ws0 + 8388608;
    u16* qkvb  = ws0 + 33554432;
    u16* attnb = ws0;
    u16* owb   = ws0 + 8388608;
    u16* vt    = ws0 + 25165824;

    conv_f32_bf16<<<2048, 256, 0, stream>>>(hidden, hb, 2048 * 4096 / 4);
    conv_f32_bf16<<<2048, 256, 0, stream>>>(Wqkv_w, wqb, 6144 * 4096 / 4);

    // QKV: M=2048, N=6144, BN=192 -> 8 x 32 = 256 blocks
    gemm8p<3, 1><<<256, 512, 0, stream>>>(hb, wqb, Wqkv_b, qkvb, 2048, 6144, 4096, 32);

    rope_bf16<<<S_LEN, 256, 0, stream>>>(qkvb, positions);
    vtrans<<<dim3(32, 8), 256, 0, stream>>>(qkvb, vt);

    conv_f32_bf16<<<2048, 256, 0, stream>>>(out_w, owb, 4096 * 4096 / 4);

    // attention: 256 blocks (16 q-blocks x 16 half-head pairs), 8 waves
    attn_bf16<<<256, 512, 0, stream>>>(qkvb, vt, attnb, lq1, lk1, lq2, lk2, subln);

    // out: M=2048, N=4096, BN=128 -> 8 x 32 = 256 blocks
    gemm8p<2, 0><<<256, 512, 0, stream>>>(attnb, owb, out_b, out, 2048, 4096, 4096, 32);
}

// Round 9
// 407.648 us; speedup vs baseline: 1.0056x; 1.0056x over previous
//
#include <hip/hip_runtime.h>

typedef unsigned short u16;
typedef __attribute__((ext_vector_type(8))) short bf16x8;
typedef __attribute__((ext_vector_type(4))) float f32x4;
typedef __attribute__((ext_vector_type(4))) unsigned short us4;
typedef __attribute__((ext_vector_type(8))) unsigned short us8;

#define S_LEN 2048
#define QKV_P 6144
#define WIN_SZ 1024
#define SCALE_F 0.08838834764831845f
#define LAMBDA_INIT_F 0.35550906759096925f
#define ONE_MINUS_LI_F 0.6444909324090308f

__device__ __forceinline__ u16 f2bf(float f) {
    union { float f; unsigned int u; } v; v.f = f;
    unsigned int u = v.u;
    return (u16)((u + 0x7fffu + ((u >> 16) & 1u)) >> 16);
}
__device__ __forceinline__ float bf2f(u16 u) {
    union { unsigned int u; float f; } v; v.u = ((unsigned int)u) << 16; return v.f;
}
__device__ __forceinline__ void gload16(const void* g, void* l) {
    __builtin_amdgcn_global_load_lds(
        (const __attribute__((address_space(1))) unsigned int*)g,
        (__attribute__((address_space(3))) unsigned int*)l, 16, 0, 0);
}

// ---------------------------------------------------------------------------
// f32 -> bf16 elementwise convert
// ---------------------------------------------------------------------------
__global__ __launch_bounds__(256)
void conv_f32_bf16(const float* __restrict__ src, u16* __restrict__ dst, int n4) {
    for (int i = blockIdx.x * 256 + threadIdx.x; i < n4; i += gridDim.x * 256) {
        float4 v = ((const float4*)src)[i];
        us4 h;
        h.x = f2bf(v.x); h.y = f2bf(v.y); h.z = f2bf(v.z); h.w = f2bf(v.w);
        ((us4*)dst)[i] = h;
    }
}

// ---------------------------------------------------------------------------
// 8-phase 256xBN GEMM, BN = NF*64.  512 thr = 8 waves (2M x 4N).
// amdgpu_waves_per_eu(2,2): pin the register budget to 256 VGPR (pool/2).
// launch_bounds' 2nd arg only sets a MIN -- the allocator still targets 4
// waves/EU and budgets 128, spilling the acc set (measured rounds 5/7/8).
// ---------------------------------------------------------------------------
template<int NR>
__device__ __forceinline__ void stage_half(const u16* __restrict__ src, int K,
                                           int gRowBase, int kcol0,
                                           u16* slot, int tid, int wid) {
#pragma unroll
    for (int g = 0; g < 2; ++g) {
        if (g * 128 + wid * 16 < NR) {   // wave-uniform
            int row = g * 128 + (tid >> 2);
            int cc = (tid & 3) ^ ((row >> 1) & 3);
            gload16(src + (size_t)(gRowBase + row) * K + kcol0 + cc * 8,
                    slot + g * 4096 + wid * 512);
        }
    }
}

__device__ __forceinline__ bf16x8 ldfrag(const u16* slot, int row, int l4) {
    int pc = l4 ^ ((row >> 1) & 3);
    return *(const bf16x8*)(slot + row * 32 + pc * 8);
}

template<int NF>
__device__ __forceinline__ void gemm_wait(int wid) {
    if constexpr (NF == 3) {
        if (wid < 4) asm volatile("s_waitcnt vmcnt(4)" ::: "memory");
        else         asm volatile("s_waitcnt vmcnt(3)" ::: "memory");
    } else if constexpr (NF == 2) {
        asm volatile("s_waitcnt vmcnt(3)" ::: "memory");
    } else {
        asm volatile("s_waitcnt vmcnt(4)" ::: "memory");
    }
}

template<int NF, int OUT_BF16>
__global__ __launch_bounds__(512)
__attribute__((amdgpu_waves_per_eu(2, 2)))
void gemm8p(const u16* __restrict__ A, const u16* __restrict__ W,
            const float* __restrict__ bias, void* __restrict__ Cv,
            int M, int N, int K, int nbx) {
    constexpr int BN = NF * 64;
    constexpr int BSLOT = NF * 2048;            // u16 per B slot
    __shared__ u16 lds[32768 + 4 * BSLOT];

    const int tid = threadIdx.x;
    const int wid = tid >> 6, lane = tid & 63;
    const int wr = wid >> 2, wc = wid & 3;
    const int l15 = lane & 15, l4 = lane >> 4;

    const int nwg = gridDim.x;
    const int q8 = nwg >> 3;
    const int swz = (blockIdx.x & 7) * q8 + (blockIdx.x >> 3);
    const int bx = swz % nbx, by = swz / nbx;
    const int rowBase = by * 256;
    const int colBase = bx * BN;

    const int NT = K >> 6;

    u16* const baseA = lds;
    u16* const baseB = lds + 32768;

    f32x4 acc[8][NF] = {};

    stage_half<256>(A, K, rowBase, 0,  baseA + 0 * 8192, tid, wid);
    stage_half<BN> (W, K, colBase, 0,  baseB + 0 * BSLOT, tid, wid);
    stage_half<256>(A, K, rowBase, 32, baseA + 1 * 8192, tid, wid);
    stage_half<BN> (W, K, colBase, 32, baseB + 1 * BSLOT, tid, wid);
    stage_half<256>(A, K, rowBase, 64, baseA + 2 * 8192, tid, wid);
    stage_half<BN> (W, K, colBase, 64, baseB + 2 * BSLOT, tid, wid);
    gemm_wait<NF>(wid);
    __builtin_amdgcn_s_barrier();

    for (int t = 0; t < NT; ++t) {
        const int b = t & 1;
        const int bn = b ^ 1;
        u16* const A0 = baseA + (b * 2 + 0) * 8192;
        u16* const A1 = baseA + (b * 2 + 1) * 8192;
        u16* const B0 = baseB + (b * 2 + 0) * BSLOT;
        u16* const B1 = baseB + (b * 2 + 1) * BSLOT;

        bf16x8 af[4], bfv[NF];

        // phase 0: kk0, m0-3
#pragma unroll
        for (int m = 0; m < 4; ++m) af[m] = ldfrag(A0, wr * 128 + m * 16 + l15, l4);
#pragma unroll
        for (int n = 0; n < NF; ++n) bfv[n] = ldfrag(B0, wc * (NF * 16) + n * 16 + l15, l4);
        if (t + 1 < NT)
            stage_half<256>(A, K, rowBase, (t + 1) * 64 + 32, baseA + (bn * 2 + 1) * 8192, tid, wid);
        __builtin_amdgcn_s_barrier();
        __builtin_amdgcn_s_setprio(1);
#pragma unroll
        for (int m = 0; m < 4; ++m)
#pragma unroll
            for (int n = 0; n < NF; ++n)
                acc[m][n] = __builtin_amdgcn_mfma_f32_16x16x32_bf16(af[m], bfv[n], acc[m][n], 0, 0, 0);
        __builtin_amdgcn_s_setprio(0);
        __builtin_amdgcn_s_barrier();

        // phase 1: kk0, m4-7
#pragma unroll
        for (int m = 0; m < 4; ++m) af[m] = ldfrag(A0, wr * 128 + (m + 4) * 16 + l15, l4);
        if (t + 1 < NT)
            stage_half<BN>(W, K, colBase, (t + 1) * 64 + 32, baseB + (bn * 2 + 1) * BSLOT, tid, wid);
        __builtin_amdgcn_s_barrier();
        __builtin_amdgcn_s_setprio(1);
#pragma unroll
        for (int m = 0; m < 4; ++m)
#pragma unroll
            for (int n = 0; n < NF; ++n)
                acc[m + 4][n] = __builtin_amdgcn_mfma_f32_16x16x32_bf16(af[m], bfv[n], acc[m + 4][n], 0, 0, 0);
        __builtin_amdgcn_s_setprio(0);
        __builtin_amdgcn_s_barrier();

        // phase 2: kk1, m0-3
#pragma unroll
        for (int m = 0; m < 4; ++m) af[m] = ldfrag(A1, wr * 128 + m * 16 + l15, l4);
#pragma unroll
        for (int n = 0; n < NF; ++n) bfv[n] = ldfrag(B1, wc * (NF * 16) + n * 16 + l15, l4);
        if (t + 2 < NT)
            stage_half<256>(A, K, rowBase, (t + 2) * 64, baseA + (b * 2 + 0) * 8192, tid, wid);
        __builtin_amdgcn_s_barrier();
        __builtin_amdgcn_s_setprio(1);
#pragma unroll
        for (int m = 0; m < 4; ++m)
#pragma unroll
            for (int n = 0; n < NF; ++n)
                acc[m][n] = __builtin_amdgcn_mfma_f32_16x16x32_bf16(af[m], bfv[n], acc[m][n], 0, 0, 0);
        __builtin_amdgcn_s_setprio(0);
        __builtin_amdgcn_s_barrier();

        // phase 3: kk1, m4-7
#pragma unroll
        for (int m = 0; m < 4; ++m) af[m] = ldfrag(A1, wr * 128 + (m + 4) * 16 + l15, l4);
        if (t + 2 < NT)
            stage_half<BN>(W, K, colBase, (t + 2) * 64, baseB + (b * 2 + 0) * BSLOT, tid, wid);
        __builtin_amdgcn_s_barrier();
        __builtin_amdgcn_s_setprio(1);
#pragma unroll
        for (int m = 0; m < 4; ++m)
#pragma unroll
            for (int n = 0; n < NF; ++n)
                acc[m + 4][n] = __builtin_amdgcn_mfma_f32_16x16x32_bf16(af[m], bfv[n], acc[m + 4][n], 0, 0, 0);
        __builtin_amdgcn_s_setprio(0);
        if (t + 2 < NT) gemm_wait<NF>(wid);
        else            asm volatile("s_waitcnt vmcnt(0)" ::: "memory");
        __builtin_amdgcn_s_barrier();
    }

#pragma unroll
    for (int n = 0; n < NF; ++n) {
        int col = colBase + wc * (NF * 16) + n * 16 + l15;
        float bs = bias[col];
#pragma unroll
        for (int m = 0; m < 8; ++m)
#pragma unroll
            for (int rr = 0; rr < 4; ++rr) {
                int rowi = rowBase + wr * 128 + m * 16 + l4 * 4 + rr;
                float v = acc[m][n][rr] + bs;
                if (OUT_BF16) ((u16*)Cv)[(size_t)rowi * N + col] = f2bf(v);
                else          ((float*)Cv)[(size_t)rowi * N + col] = v;
            }
    }
}

// ---------------------------------------------------------------------------
// RoPE in-place on bf16 qkv.
// ---------------------------------------------------------------------------
__global__ __launch_bounds__(256)
void rope_bf16(u16* __restrict__ qkv, const int* __restrict__ positions) {
    const int row = blockIdx.x;
    const float pos = (float)positions[row];
    for (int idx = threadIdx.x; idx < 640; idx += 256) {
        int head = idx >> 4;
        int g = idx & 15;
        int base = (head < 32) ? head * 128 : 4096 + (head - 32) * 128;
        u16* p = qkv + (size_t)row * QKV_P + base + g * 4;
        us4 x1 = *(us4*)p;
        us4 x2 = *(us4*)(p + 64);
#pragma unroll
        for (int j = 0; j < 4; ++j) {
            float inv_freq = __expf(-(float)(g * 4 + j) * (9.210340371976184f / 64.0f));
            float ang = pos * inv_freq;
            float s, c;
            sincosf(ang, &s, &c);
            float a = bf2f(x1[j]), b = bf2f(x2[j]);
            x1[j] = f2bf(a * c - b * s);
            x2[j] = f2bf(b * c + a * s);
        }
        *(us4*)p = x1;
        *(us4*)(p + 64) = x2;
    }
}

// ---------------------------------------------------------------------------
// V transpose: qkv V-region -> vt[a][d][s].
// ---------------------------------------------------------------------------
__global__ __launch_bounds__(256)
void vtrans(const u16* __restrict__ qkv, u16* __restrict__ vt) {
    __shared__ u16 T[128 * 72];
    const int s0 = blockIdx.x * 64;
    const int a = blockIdx.y;
    const u16* src = qkv + 5120 + a * 128;
#pragma unroll
    for (int it = 0; it < 4; ++it) {
        int idx = it * 256 + threadIdx.x;
        int s = idx >> 4;
        int c8 = idx & 15;
        us8 v = *(const us8*)(src + (size_t)(s0 + s) * QKV_P + c8 * 8);
        int sc = s >> 3, su = s & 7;
#pragma unroll
        for (int j = 0; j < 8; ++j) {
            int d = c8 * 8 + j;
            T[d * 72 + ((sc ^ ((d >> 3) & 7)) * 8 + su)] = v[j];
        }
    }
    __syncthreads();
#pragma unroll
    for (int it = 0; it < 4; ++it) {
        int idx = it * 256 + threadIdx.x;
        int d = idx >> 3, sc = idx & 7;
        us8 v = *(const us8*)&T[d * 72 + ((sc ^ ((d >> 3) & 7)) * 8)];
        *(us8*)(vt + (size_t)a * 262144 + (size_t)d * 2048 + s0 + sc * 8) = v;
    }
}

// ---------------------------------------------------------------------------
// Dual-stream sliding-window flash attention + fused RMS-norm.
// 256 blocks (128 q-rows x half-head-pair), 8 waves. K/V double-buffered
// (stage t+1 at tile top, ONE vmcnt(0)+barrier per tile). P per-wave private.
// LDS 144 KB -> 1 block/CU. amdgpu_waves_per_eu(2,2) pins the VGPR budget to
// 256 (the ~230-reg acc set spills at the default 128 budget -- measured
// rounds 5/7/8: +25MB scratch writes/pass, MfmaUtil stuck at 10%).
// ---------------------------------------------------------------------------
__global__ __launch_bounds__(512)
__attribute__((amdgpu_waves_per_eu(2, 2)))
void attn_bf16(const u16* __restrict__ qkv, const u16* __restrict__ vtg,
               u16* __restrict__ attnb,
               const float* __restrict__ lq1, const float* __restrict__ lk1,
               const float* __restrict__ lq2, const float* __restrict__ lk2,
               const float* __restrict__ subln) {
    __shared__ u16 Kb[2][2][64 * 128];   // [buf][stream] 64 KB
    __shared__ u16 Vb[2][2][128 * 64];   // [buf][stream] 64 KB
    __shared__ u16 Pw[8][16 * 64];       // per-wave P, 16 KB

    const int tid = threadIdx.x;
    const int w = tid >> 6, lane = tid & 63;
    const int l15 = lane & 15, l4 = lane >> 4;

    const int qb = blockIdx.x & 15;
    const int h  = blockIdx.x >> 4;
    const int q0 = qb * 128;
    const int h1 = 2 * h, h2 = 2 * h + 1;
    const int a1 = 2 * (h >> 2), a2 = a1 + 1;

    // Q fragments: wave w owns q-rows q0 + w*16 .. +15
    bf16x8 q1f[4], q2f[4];
    {
        int qrow = q0 + w * 16 + l15;
        const u16* qp1 = qkv + (size_t)qrow * QKV_P + h1 * 128;
        const u16* qp2 = qkv + (size_t)qrow * QKV_P + h2 * 128;
#pragma unroll
        for (int kk = 0; kk < 4; ++kk) {
            q1f[kk] = *(const bf16x8*)(qp1 + kk * 32 + l4 * 8);
            q2f[kk] = *(const bf16x8*)(qp2 + kk * 32 + l4 * 8);
        }
    }

    f32x4 a11[8] = {}, a12[8] = {}, a21[8] = {}, a22[8] = {};
    float m1[4], l1[4], m2[4], l2[4];
#pragma unroll
    for (int r = 0; r < 4; ++r) { m1[r] = -1e30f; l1[r] = 0.f; m2[r] = -1e30f; l2[r] = 0.f; }

    const int kr4 = lane >> 4;   // K stage: row within 4-row chunk
    const int kc  = lane & 15;
    const int vd8 = lane >> 3;   // V stage: d-row within 8-row chunk
    const int vc  = lane & 7;

    const int tbeg = (qb >= 8) ? ((q0 - (WIN_SZ - 1)) >> 6) : 0;
    const int tend = (q0 + 127) >> 6;

#define STAGE_TILE(T, NB)                                                      \
    {                                                                          \
        const int kv0s = (T) * 64;                                             \
        _Pragma("unroll")                                                      \
        for (int s = 0; s < 2; ++s) {                                          \
            int ch = w * 2 + s;                                                \
            int krow = ch * 4 + kr4;                                           \
            int kcs = (kc ^ (krow & 7)) * 8;                                   \
            const u16* kbase = qkv + (size_t)(kv0s + krow) * QKV_P + 4096;     \
            gload16(kbase + a1 * 128 + kcs, &Kb[NB][0][ch * 512]);             \
            gload16(kbase + a2 * 128 + kcs, &Kb[NB][1][ch * 512]);             \
            int vdrow = ch * 8 + vd8;                                          \
            int vcs = (vc ^ (vdrow & 7)) * 8;                                  \
            const u16* vbase = vtg + (size_t)vdrow * 2048 + kv0s + vcs;        \
            gload16(vbase + (size_t)a1 * 262144, &Vb[NB][0][ch * 512]);        \
            gload16(vbase + (size_t)a2 * 262144, &Vb[NB][1][ch * 512]);        \
        }                                                                      \
    }

    // prologue
    STAGE_TILE(tbeg, 0);
    asm volatile("s_waitcnt vmcnt(0)" ::: "memory");
    __builtin_amdgcn_s_barrier();
    asm volatile("" ::: "memory");

    int cb = 0;
    for (int t = tbeg; t <= tend; ++t) {
        const int kv0 = t * 64;

        // issue next tile's stage first (latency hides under whole tile)
        if (t < tend) STAGE_TILE(t + 1, cb ^ 1);

        // --- QK^T from buf cb
        f32x4 sc1[4], sc2[4];
        __builtin_amdgcn_s_setprio(1);
#pragma unroll
        for (int c = 0; c < 4; ++c) {
            f32x4 s1 = {0.f, 0.f, 0.f, 0.f};
            f32x4 s2 = {0.f, 0.f, 0.f, 0.f};
#pragma unroll
            for (int kk = 0; kk < 4; ++kk) {
                int off = (c * 16 + l15) * 128 + (((kk * 4 + l4) ^ (l15 & 7)) * 8);
                bf16x8 kf1 = *(const bf16x8*)&Kb[cb][0][off];
                bf16x8 kf2 = *(const bf16x8*)&Kb[cb][1][off];
                s1 = __builtin_amdgcn_mfma_f32_16x16x32_bf16(q1f[kk], kf1, s1, 0, 0, 0);
                s2 = __builtin_amdgcn_mfma_f32_16x16x32_bf16(q2f[kk], kf2, s2, 0, 0, 0);
            }
            sc1[c] = s1; sc2[c] = s2;
        }
        __builtin_amdgcn_s_setprio(0);

        // --- masks: causal zone (last 2 tiles), window zone (first 2, qb>=8)
        const bool dz = (t >= tend - 1);
        const bool wz = (qb >= 8) && (t <= tbeg + 1);
        if (dz) {
#pragma unroll
            for (int c = 0; c < 4; ++c) {
                int j = kv0 + c * 16 + l15;
#pragma unroll
                for (int r = 0; r < 4; ++r) {
                    int i = q0 + w * 16 + l4 * 4 + r;
                    if (j > i) { sc1[c][r] = -1e30f; sc2[c][r] = -1e30f; }
                }
            }
        } else if (wz) {
#pragma unroll
            for (int c = 0; c < 4; ++c) {
                int j = kv0 + c * 16 + l15;
#pragma unroll
                for (int r = 0; r < 4; ++r) {
                    int i = q0 + w * 16 + l4 * 4 + r;
                    if (i - j >= WIN_SZ) { sc1[c][r] = -1e30f; sc2[c][r] = -1e30f; }
                }
            }
        }

        // --- row max + defer-max rescale
        float rmax1[4], rmax2[4];
#pragma unroll
        for (int r = 0; r < 4; ++r) {
            rmax1[r] = fmaxf(fmaxf(sc1[0][r], sc1[1][r]), fmaxf(sc1[2][r], sc1[3][r]));
            rmax2[r] = fmaxf(fmaxf(sc2[0][r], sc2[1][r]), fmaxf(sc2[2][r], sc2[3][r]));
        }
#pragma unroll
        for (int msk = 1; msk < 16; msk <<= 1)
#pragma unroll
            for (int r = 0; r < 4; ++r) {
                rmax1[r] = fmaxf(rmax1[r], __shfl_xor(rmax1[r], msk));
                rmax2[r] = fmaxf(rmax2[r], __shfl_xor(rmax2[r], msk));
            }
        bool need = false;
#pragma unroll
        for (int r = 0; r < 4; ++r)
            need = need || (rmax1[r] > m1[r] + 32.0f) || (rmax2[r] > m2[r] + 32.0f);
        if (__any(need)) {
            float f1[4], f2[4];
#pragma unroll
            for (int r = 0; r < 4; ++r) {
                float nm1 = fmaxf(m1[r], rmax1[r]);
                float nm2 = fmaxf(m2[r], rmax2[r]);
                f1[r] = __expf((m1[r] - nm1) * SCALE_F);
                f2[r] = __expf((m2[r] - nm2) * SCALE_F);
                m1[r] = nm1; m2[r] = nm2;
                l1[r] *= f1[r]; l2[r] *= f2[r];
            }
#pragma unroll
            for (int f = 0; f < 8; ++f)
#pragma unroll
                for (int r = 0; r < 4; ++r) {
                    a11[f][r] *= f1[r]; a12[f][r] *= f1[r];
                    a21[f][r] *= f2[r]; a22[f][r] *= f2[r];
                }
        }

        // --- P = exp((s-m)*SCALE); rowsum; stream-1 P to LDS (wave-private)
        float rs1[4] = {0.f, 0.f, 0.f, 0.f}, rs2[4] = {0.f, 0.f, 0.f, 0.f};
#pragma unroll
        for (int c = 0; c < 4; ++c) {
            int col = c * 16 + l15;
#pragma unroll
            for (int r = 0; r < 4; ++r) {
                int prow = l4 * 4 + r;
                float p1 = __expf((sc1[c][r] - m1[r]) * SCALE_F);
                float p2 = __expf((sc2[c][r] - m2[r]) * SCALE_F);
                if (wz) {
                    if (m1[r] < -1e29f) p1 = 0.f;
                    if (m2[r] < -1e29f) p2 = 0.f;
                }
                rs1[r] += p1; rs2[r] += p2;
                sc2[c][r] = p2;   // keep stream-2 P in regs for after PV1
                int pco = ((col >> 3) ^ (prow & 7)) * 8 + (col & 7);
                Pw[w][prow * 64 + pco] = f2bf(p1);
            }
        }
#pragma unroll
        for (int msk = 1; msk < 16; msk <<= 1)
#pragma unroll
            for (int r = 0; r < 4; ++r) {
                rs1[r] += __shfl_xor(rs1[r], msk);
                rs2[r] += __shfl_xor(rs2[r], msk);
            }
#pragma unroll
        for (int r = 0; r < 4; ++r) { l1[r] += rs1[r]; l2[r] += rs2[r]; }

        // --- PV stream 1 (a11 += P1*V1, a12 += P1*V2)
        __builtin_amdgcn_s_setprio(1);
#pragma unroll
        for (int kk = 0; kk < 2; ++kk) {
            int pch = ((kk * 4 + l4) ^ (l15 & 7)) * 8;
            bf16x8 pa = *(const bf16x8*)&Pw[w][l15 * 64 + pch];
#pragma unroll
            for (int f = 0; f < 8; ++f) {
                int off = (f * 16 + l15) * 64 + (((kk * 4 + l4) ^ (l15 & 7)) * 8);
                bf16x8 vb1 = *(const bf16x8*)&Vb[cb][0][off];
                bf16x8 vb2 = *(const bf16x8*)&Vb[cb][1][off];
                a11[f] = __builtin_amdgcn_mfma_f32_16x16x32_bf16(pa, vb1, a11[f], 0, 0, 0);
                a12[f] = __builtin_amdgcn_mfma_f32_16x16x32_bf16(pa, vb2, a12[f], 0, 0, 0);
            }
        }
        __builtin_amdgcn_s_setprio(0);

        // --- stream-2 P to LDS (same wave-private buffer), then PV stream 2
#pragma unroll
        for (int c = 0; c < 4; ++c) {
            int col = c * 16 + l15;
#pragma unroll
            for (int r = 0; r < 4; ++r) {
                int prow = l4 * 4 + r;
                int pco = ((col >> 3) ^ (prow & 7)) * 8 + (col & 7);
                Pw[w][prow * 64 + pco] = f2bf(sc2[c][r]);
            }
        }
        __builtin_amdgcn_s_setprio(1);
#pragma unroll
        for (int kk = 0; kk < 2; ++kk) {
            int pch = ((kk * 4 + l4) ^ (l15 & 7)) * 8;
            bf16x8 pa = *(const bf16x8*)&Pw[w][l15 * 64 + pch];
#pragma unroll
            for (int f = 0; f < 8; ++f) {
                int off = (f * 16 + l15) * 64 + (((kk * 4 + l4) ^ (l15 & 7)) * 8);
                bf16x8 vb1 = *(const bf16x8*)&Vb[cb][0][off];
                bf16x8 vb2 = *(const bf16x8*)&Vb[cb][1][off];
                a21[f] = __builtin_amdgcn_mfma_f32_16x16x32_bf16(pa, vb1, a21[f], 0, 0, 0);
                a22[f] = __builtin_amdgcn_mfma_f32_16x16x32_bf16(pa, vb2, a22[f], 0, 0, 0);
            }
        }
        __builtin_amdgcn_s_setprio(0);

        // --- single sync point: next tile staged + everyone done with buf cb
        asm volatile("s_waitcnt vmcnt(0)" ::: "memory");
        __builtin_amdgcn_s_barrier();
        asm volatile("" ::: "memory");
        cb ^= 1;
    }

    // lambda scalar
    float s1v = lq1[lane] * lk1[lane] + lq1[lane + 64] * lk1[lane + 64];
    float s2v = lq2[lane] * lk2[lane] + lq2[lane + 64] * lk2[lane + 64];
#pragma unroll
    for (int msk = 1; msk < 64; msk <<= 1) {
        s1v += __shfl_xor(s1v, msk);
        s2v += __shfl_xor(s2v, msk);
    }
    const float lam = __expf(s1v) - __expf(s2v) + LAMBDA_INIT_F;

    float sw0[8], sw1[8];
#pragma unroll
    for (int f = 0; f < 8; ++f) {
        sw0[f] = subln[f * 16 + l15];
        sw1[f] = subln[128 + f * 16 + l15];
    }

#pragma unroll
    for (int r = 0; r < 4; ++r) {
        float inv1 = 1.0f / l1[r];
        float inv2 = 1.0f / l2[r];
        float o0[8], o1[8];
        float ssq = 0.f;
#pragma unroll
        for (int f = 0; f < 8; ++f) {
            o0[f] = a11[f][r] * inv1 - lam * (a21[f][r] * inv2);
            o1[f] = a12[f][r] * inv1 - lam * (a22[f][r] * inv2);
            ssq += o0[f] * o0[f] + o1[f] * o1[f];
        }
#pragma unroll
        for (int msk = 1; msk < 16; msk <<= 1) ssq += __shfl_xor(ssq, msk);
        float scale = rsqrtf(ssq * (1.0f / 256.0f) + 1e-5f) * ONE_MINUS_LI_F;
        int row = q0 + w * 16 + l4 * 4 + r;
        u16* op = attnb + (size_t)row * 4096 + h * 256;
#pragma unroll
        for (int f = 0; f < 8; ++f) {
            op[f * 16 + l15]       = f2bf(o0[f] * scale * sw0[f]);
            op[128 + f * 16 + l15] = f2bf(o1[f] * scale * sw1[f]);
        }
    }
}

// ---------------------------------------------------------------------------
extern "C" void kernel_launch(void* const* d_in, const int* in_sizes, int n_in,
                              void* d_out, int out_size, void* d_ws, size_t ws_size,
                              hipStream_t stream) {
    const float* hidden    = (const float*)d_in[0];
    const int*   positions = (const int*)d_in[1];
    const float* Wqkv_w    = (const float*)d_in[2];
    const float* Wqkv_b    = (const float*)d_in[3];
    const float* out_w     = (const float*)d_in[4];
    const float* out_b     = (const float*)d_in[5];
    const float* lq1       = (const float*)d_in[6];
    const float* lk1       = (const float*)d_in[7];
    const float* lq2       = (const float*)d_in[8];
    const float* lk2       = (const float*)d_in[9];
    const float* subln     = (const float*)d_in[10];
    float* out = (float*)d_out;

    u16* ws0   = (u16*)d_ws;
    u16* hb    = ws0;
    u16* wqb   = ws0 + 8388608;
    u16* qkvb  = ws0 + 33554432;
    u16* attnb = ws0;
    u16* owb   = ws0 + 8388608;
    u16* vt    = ws0 + 25165824;

    conv_f32_bf16<<<2048, 256, 0, stream>>>(hidden, hb, 2048 * 4096 / 4);
    conv_f32_bf16<<<2048, 256, 0, stream>>>(Wqkv_w, wqb, 6144 * 4096 / 4);

    // QKV: M=2048, N=6144, BN=192 -> 8 x 32 = 256 blocks
    gemm8p<3, 1><<<256, 512, 0, stream>>>(hb, wqb, Wqkv_b, qkvb, 2048, 6144, 4096, 32);

    rope_bf16<<<S_LEN, 256, 0, stream>>>(qkvb, positions);
    vtrans<<<dim3(32, 8), 256, 0, stream>>>(qkvb, vt);

    conv_f32_bf16<<<2048, 256, 0, stream>>>(out_w, owb, 4096 * 4096 / 4);

    // attention: 256 blocks (16 q-blocks x 16 half-head pairs), 8 waves
    attn_bf16<<<256, 512, 0, stream>>>(qkvb, vt, attnb, lq1, lk1, lq2, lk2, subln);

    // out: M=2048, N=4096, BN=128 -> 8 x 32 = 256 blocks
    gemm8p<2, 0><<<256, 512, 0, stream>>>(attnb, owb, out_b, out, 2048, 4096, 4096, 32);
}

// Round 10
// 362.918 us; speedup vs baseline: 1.1295x; 1.1233x over previous
//
#include <hip/hip_runtime.h>

typedef unsigned short u16;
typedef __attribute__((ext_vector_type(8))) short bf16x8;
typedef __attribute__((ext_vector_type(4))) float f32x4;
typedef __attribute__((ext_vector_type(4))) unsigned short us4;
typedef __attribute__((ext_vector_type(8))) unsigned short us8;

#define S_LEN 2048
#define QKV_P 6144
#define WIN_SZ 1024
#define SCALE_F 0.08838834764831845f
#define LAMBDA_INIT_F 0.35550906759096925f
#define ONE_MINUS_LI_F 0.6444909324090308f

__device__ __forceinline__ u16 f2bf(float f) {
    union { float f; unsigned int u; } v; v.f = f;
    unsigned int u = v.u;
    return (u16)((u + 0x7fffu + ((u >> 16) & 1u)) >> 16);
}
__device__ __forceinline__ float bf2f(u16 u) {
    union { unsigned int u; float f; } v; v.u = ((unsigned int)u) << 16; return v.f;
}
__device__ __forceinline__ void gload16(const void* g, void* l) {
    __builtin_amdgcn_global_load_lds(
        (const __attribute__((address_space(1))) unsigned int*)g,
        (__attribute__((address_space(3))) unsigned int*)l, 16, 0, 0);
}

// ---------------------------------------------------------------------------
// f32 -> bf16 elementwise convert
// ---------------------------------------------------------------------------
__global__ __launch_bounds__(256)
void conv_f32_bf16(const float* __restrict__ src, u16* __restrict__ dst, int n4) {
    for (int i = blockIdx.x * 256 + threadIdx.x; i < n4; i += gridDim.x * 256) {
        float4 v = ((const float4*)src)[i];
        us4 h;
        h.x = f2bf(v.x); h.y = f2bf(v.y); h.z = f2bf(v.z); h.w = f2bf(v.w);
        ((us4*)dst)[i] = h;
    }
}

// ---------------------------------------------------------------------------
// 8-phase 256xBN GEMM, BN = NF*64.  512 thr = 8 waves (2M x 4N).
// ---------------------------------------------------------------------------
template<int NR>
__device__ __forceinline__ void stage_half(const u16* __restrict__ src, int K,
                                           int gRowBase, int kcol0,
                                           u16* slot, int tid, int wid) {
#pragma unroll
    for (int g = 0; g < 2; ++g) {
        if (g * 128 + wid * 16 < NR) {   // wave-uniform
            int row = g * 128 + (tid >> 2);
            int cc = (tid & 3) ^ ((row >> 1) & 3);
            gload16(src + (size_t)(gRowBase + row) * K + kcol0 + cc * 8,
                    slot + g * 4096 + wid * 512);
        }
    }
}

__device__ __forceinline__ bf16x8 ldfrag(const u16* slot, int row, int l4) {
    int pc = l4 ^ ((row >> 1) & 3);
    return *(const bf16x8*)(slot + row * 32 + pc * 8);
}

template<int NF>
__device__ __forceinline__ void gemm_wait(int wid) {
    if constexpr (NF == 3) {
        if (wid < 4) asm volatile("s_waitcnt vmcnt(4)" ::: "memory");
        else         asm volatile("s_waitcnt vmcnt(3)" ::: "memory");
    } else if constexpr (NF == 2) {
        asm volatile("s_waitcnt vmcnt(3)" ::: "memory");
    } else {
        asm volatile("s_waitcnt vmcnt(4)" ::: "memory");
    }
}

template<int NF, int OUT_BF16>
__global__ __launch_bounds__(512)
__attribute__((amdgpu_waves_per_eu(2, 2)))
void gemm8p(const u16* __restrict__ A, const u16* __restrict__ W,
            const float* __restrict__ bias, void* __restrict__ Cv,
            int M, int N, int K, int nbx) {
    constexpr int BN = NF * 64;
    constexpr int BSLOT = NF * 2048;            // u16 per B slot
    __shared__ u16 lds[32768 + 4 * BSLOT];

    const int tid = threadIdx.x;
    const int wid = tid >> 6, lane = tid & 63;
    const int wr = wid >> 2, wc = wid & 3;
    const int l15 = lane & 15, l4 = lane >> 4;

    const int nwg = gridDim.x;
    const int q8 = nwg >> 3;
    const int swz = (blockIdx.x & 7) * q8 + (blockIdx.x >> 3);
    const int bx = swz % nbx, by = swz / nbx;
    const int rowBase = by * 256;
    const int colBase = bx * BN;

    const int NT = K >> 6;

    u16* const baseA = lds;
    u16* const baseB = lds + 32768;

    f32x4 acc[8][NF] = {};

    stage_half<256>(A, K, rowBase, 0,  baseA + 0 * 8192, tid, wid);
    stage_half<BN> (W, K, colBase, 0,  baseB + 0 * BSLOT, tid, wid);
    stage_half<256>(A, K, rowBase, 32, baseA + 1 * 8192, tid, wid);
    stage_half<BN> (W, K, colBase, 32, baseB + 1 * BSLOT, tid, wid);
    stage_half<256>(A, K, rowBase, 64, baseA + 2 * 8192, tid, wid);
    stage_half<BN> (W, K, colBase, 64, baseB + 2 * BSLOT, tid, wid);
    gemm_wait<NF>(wid);
    __builtin_amdgcn_s_barrier();

    for (int t = 0; t < NT; ++t) {
        const int b = t & 1;
        const int bn = b ^ 1;
        u16* const A0 = baseA + (b * 2 + 0) * 8192;
        u16* const A1 = baseA + (b * 2 + 1) * 8192;
        u16* const B0 = baseB + (b * 2 + 0) * BSLOT;
        u16* const B1 = baseB + (b * 2 + 1) * BSLOT;

        bf16x8 af[4], bfv[NF];

        // phase 0: kk0, m0-3
#pragma unroll
        for (int m = 0; m < 4; ++m) af[m] = ldfrag(A0, wr * 128 + m * 16 + l15, l4);
#pragma unroll
        for (int n = 0; n < NF; ++n) bfv[n] = ldfrag(B0, wc * (NF * 16) + n * 16 + l15, l4);
        if (t + 1 < NT)
            stage_half<256>(A, K, rowBase, (t + 1) * 64 + 32, baseA + (bn * 2 + 1) * 8192, tid, wid);
        __builtin_amdgcn_s_barrier();
        __builtin_amdgcn_s_setprio(1);
#pragma unroll
        for (int m = 0; m < 4; ++m)
#pragma unroll
            for (int n = 0; n < NF; ++n)
                acc[m][n] = __builtin_amdgcn_mfma_f32_16x16x32_bf16(af[m], bfv[n], acc[m][n], 0, 0, 0);
        __builtin_amdgcn_s_setprio(0);
        __builtin_amdgcn_s_barrier();

        // phase 1: kk0, m4-7
#pragma unroll
        for (int m = 0; m < 4; ++m) af[m] = ldfrag(A0, wr * 128 + (m + 4) * 16 + l15, l4);
        if (t + 1 < NT)
            stage_half<BN>(W, K, colBase, (t + 1) * 64 + 32, baseB + (bn * 2 + 1) * BSLOT, tid, wid);
        __builtin_amdgcn_s_barrier();
        __builtin_amdgcn_s_setprio(1);
#pragma unroll
        for (int m = 0; m < 4; ++m)
#pragma unroll
            for (int n = 0; n < NF; ++n)
                acc[m + 4][n] = __builtin_amdgcn_mfma_f32_16x16x32_bf16(af[m], bfv[n], acc[m + 4][n], 0, 0, 0);
        __builtin_amdgcn_s_setprio(0);
        __builtin_amdgcn_s_barrier();

        // phase 2: kk1, m0-3
#pragma unroll
        for (int m = 0; m < 4; ++m) af[m] = ldfrag(A1, wr * 128 + m * 16 + l15, l4);
#pragma unroll
        for (int n = 0; n < NF; ++n) bfv[n] = ldfrag(B1, wc * (NF * 16) + n * 16 + l15, l4);
        if (t + 2 < NT)
            stage_half<256>(A, K, rowBase, (t + 2) * 64, baseA + (b * 2 + 0) * 8192, tid, wid);
        __builtin_amdgcn_s_barrier();
        __builtin_amdgcn_s_setprio(1);
#pragma unroll
        for (int m = 0; m < 4; ++m)
#pragma unroll
            for (int n = 0; n < NF; ++n)
                acc[m][n] = __builtin_amdgcn_mfma_f32_16x16x32_bf16(af[m], bfv[n], acc[m][n], 0, 0, 0);
        __builtin_amdgcn_s_setprio(0);
        __builtin_amdgcn_s_barrier();

        // phase 3: kk1, m4-7
#pragma unroll
        for (int m = 0; m < 4; ++m) af[m] = ldfrag(A1, wr * 128 + (m + 4) * 16 + l15, l4);
        if (t + 2 < NT)
            stage_half<BN>(W, K, colBase, (t + 2) * 64, baseB + (b * 2 + 0) * BSLOT, tid, wid);
        __builtin_amdgcn_s_barrier();
        __builtin_amdgcn_s_setprio(1);
#pragma unroll
        for (int m = 0; m < 4; ++m)
#pragma unroll
            for (int n = 0; n < NF; ++n)
                acc[m + 4][n] = __builtin_amdgcn_mfma_f32_16x16x32_bf16(af[m], bfv[n], acc[m + 4][n], 0, 0, 0);
        __builtin_amdgcn_s_setprio(0);
        if (t + 2 < NT) gemm_wait<NF>(wid);
        else            asm volatile("s_waitcnt vmcnt(0)" ::: "memory");
        __builtin_amdgcn_s_barrier();
    }

#pragma unroll
    for (int n = 0; n < NF; ++n) {
        int col = colBase + wc * (NF * 16) + n * 16 + l15;
        float bs = bias[col];
#pragma unroll
        for (int m = 0; m < 8; ++m)
#pragma unroll
            for (int rr = 0; rr < 4; ++rr) {
                int rowi = rowBase + wr * 128 + m * 16 + l4 * 4 + rr;
                float v = acc[m][n][rr] + bs;
                if (OUT_BF16) ((u16*)Cv)[(size_t)rowi * N + col] = f2bf(v);
                else          ((float*)Cv)[(size_t)rowi * N + col] = v;
            }
    }
}

// ---------------------------------------------------------------------------
// RoPE in-place on bf16 qkv.
// ---------------------------------------------------------------------------
__global__ __launch_bounds__(256)
void rope_bf16(u16* __restrict__ qkv, const int* __restrict__ positions) {
    const int row = blockIdx.x;
    const float pos = (float)positions[row];
    for (int idx = threadIdx.x; idx < 640; idx += 256) {
        int head = idx >> 4;
        int g = idx & 15;
        int base = (head < 32) ? head * 128 : 4096 + (head - 32) * 128;
        u16* p = qkv + (size_t)row * QKV_P + base + g * 4;
        us4 x1 = *(us4*)p;
        us4 x2 = *(us4*)(p + 64);
#pragma unroll
        for (int j = 0; j < 4; ++j) {
            float inv_freq = __expf(-(float)(g * 4 + j) * (9.210340371976184f / 64.0f));
            float ang = pos * inv_freq;
            float s, c;
            sincosf(ang, &s, &c);
            float a = bf2f(x1[j]), b = bf2f(x2[j]);
            x1[j] = f2bf(a * c - b * s);
            x2[j] = f2bf(b * c + a * s);
        }
        *(us4*)p = x1;
        *(us4*)(p + 64) = x2;
    }
}

// ---------------------------------------------------------------------------
// V transpose: qkv V-region -> vt[a][d][s].
// ---------------------------------------------------------------------------
__global__ __launch_bounds__(256)
void vtrans(const u16* __restrict__ qkv, u16* __restrict__ vt) {
    __shared__ u16 T[128 * 72];
    const int s0 = blockIdx.x * 64;
    const int a = blockIdx.y;
    const u16* src = qkv + 5120 + a * 128;
#pragma unroll
    for (int it = 0; it < 4; ++it) {
        int idx = it * 256 + threadIdx.x;
        int s = idx >> 4;
        int c8 = idx & 15;
        us8 v = *(const us8*)(src + (size_t)(s0 + s) * QKV_P + c8 * 8);
        int sc = s >> 3, su = s & 7;
#pragma unroll
        for (int j = 0; j < 8; ++j) {
            int d = c8 * 8 + j;
            T[d * 72 + ((sc ^ ((d >> 3) & 7)) * 8 + su)] = v[j];
        }
    }
    __syncthreads();
#pragma unroll
    for (int it = 0; it < 4; ++it) {
        int idx = it * 256 + threadIdx.x;
        int d = idx >> 3, sc = idx & 7;
        us8 v = *(const us8*)&T[d * 72 + ((sc ^ ((d >> 3) & 7)) * 8)];
        *(us8*)(vt + (size_t)a * 262144 + (size_t)d * 2048 + s0 + sc * 8) = v;
    }
}

// ---------------------------------------------------------------------------
// STREAM-SPLIT dual-stream sliding-window flash attention + fused RMS-norm.
// 512 blocks (64 q-rows x head-pair), 8 waves: wave w -> row-group g=w&3,
// stream s=w>>2. Each wave: QK^T_s (16 MFMA), softmax_s, PV vs BOTH V halves
// (32 MFMA) -> 64 acc floats/thread (half of the fused version; the fused
// 128-float acc spilled at the 512-thread 128-VGPR cap, rounds 7-9:
// +25MB scratch writes, 171us). Differential combine via f32 LDS overlay.
// LDS 144 KB -> 1 block/CU, 2 waves/SIMD.
// ---------------------------------------------------------------------------
__global__ __launch_bounds__(512)
__attribute__((amdgpu_waves_per_eu(2, 2)))
void attn_bf16(const u16* __restrict__ qkv, const u16* __restrict__ vtg,
               u16* __restrict__ attnb,
               const float* __restrict__ lq1, const float* __restrict__ lk1,
               const float* __restrict__ lq2, const float* __restrict__ lk2,
               const float* __restrict__ subln) {
    __shared__ u16 smem[73728];   // 144 KB
    // [0,32768)      K: 4 slots (buf x stream) of 8192 u16 (64 rows x 128)
    // [32768,65536)  V: 4 slots (buf x stream) of 8192 u16 (128 d x 64 s)
    // [65536,73728)  P: 8 waves x 1024 u16 (16 rows x 64)
    // epilogue: f32 Cmb[64][264] overlays [0, 67584 B) (K/V dead)
#define KBUF(b, st) (smem + ((b) * 2 + (st)) * 8192)
#define VBUF(b, st) (smem + 32768 + ((b) * 2 + (st)) * 8192)

    const int tid = threadIdx.x;
    const int w = tid >> 6, lane = tid & 63;
    const int g = w & 3, sid = w >> 2;
    const int l15 = lane & 15, l4 = lane >> 4;
    u16* const Pw = smem + 65536 + w * 1024;

    // heavy/light complementary remap (heavy qb 16-31 first)
    int qb, h;
    {
        int i = blockIdx.x;
        if (i < 256) { qb = 16 + (i & 15); h = i >> 4; }
        else         { int j = i - 256; qb = j & 15; h = j >> 4; }
    }
    const int q0 = qb * 64;
    const int a1 = 2 * (h >> 2), a2 = a1 + 1;

    // Q fragments for this wave's stream
    bf16x8 qf[4];
    {
        int qrow = q0 + g * 16 + l15;
        const u16* qp = qkv + (size_t)qrow * QKV_P + (2 * h + sid) * 128;
#pragma unroll
        for (int kk = 0; kk < 4; ++kk)
            qf[kk] = *(const bf16x8*)(qp + kk * 32 + l4 * 8);
    }

    f32x4 aV1[8] = {}, aV2[8] = {};
    float m[4], l[4];
#pragma unroll
    for (int r = 0; r < 4; ++r) { m[r] = -1e30f; l[r] = 0.f; }

    const int kr4 = lane >> 4, kc = lane & 15;
    const int vd8 = lane >> 3, vc = lane & 7;

    const int tbeg = (qb >= 16) ? (qb - 16) : 0;
    const int tend = qb;

#define STAGE_TILE(T, NB)                                                      \
    {                                                                          \
        const int kv0s = (T) * 64;                                             \
        _Pragma("unroll")                                                      \
        for (int s2 = 0; s2 < 2; ++s2) {                                       \
            int ch = w * 2 + s2;                                               \
            int krow = ch * 4 + kr4;                                           \
            int kcs = (kc ^ (krow & 7)) * 8;                                   \
            const u16* kbase = qkv + (size_t)(kv0s + krow) * QKV_P + 4096;     \
            gload16(kbase + a1 * 128 + kcs, KBUF(NB, 0) + ch * 512);           \
            gload16(kbase + a2 * 128 + kcs, KBUF(NB, 1) + ch * 512);           \
            int vdrow = ch * 8 + vd8;                                          \
            int vcs = (vc ^ (vdrow & 7)) * 8;                                  \
            const u16* vbase = vtg + (size_t)vdrow * 2048 + kv0s + vcs;        \
            gload16(vbase + (size_t)a1 * 262144, VBUF(NB, 0) + ch * 512);      \
            gload16(vbase + (size_t)a2 * 262144, VBUF(NB, 1) + ch * 512);      \
        }                                                                      \
    }

    // prologue
    STAGE_TILE(tbeg, 0);
    asm volatile("s_waitcnt vmcnt(0)" ::: "memory");
    __builtin_amdgcn_s_barrier();
    asm volatile("" ::: "memory");

    int cb = 0;
    for (int t = tbeg; t <= tend; ++t) {
        const int kv0 = t * 64;

        // issue next tile's stage (latency hides under whole tile's compute)
        if (t < tend) STAGE_TILE(t + 1, cb ^ 1);

        // --- QK^T (this wave's stream only)
        f32x4 sc[4];
        const u16* Kc = KBUF(cb, sid);
        __builtin_amdgcn_s_setprio(1);
#pragma unroll
        for (int c = 0; c < 4; ++c) {
            f32x4 s1 = {0.f, 0.f, 0.f, 0.f};
#pragma unroll
            for (int kk = 0; kk < 4; ++kk) {
                int off = (c * 16 + l15) * 128 + (((kk * 4 + l4) ^ (l15 & 7)) * 8);
                s1 = __builtin_amdgcn_mfma_f32_16x16x32_bf16(qf[kk], *(const bf16x8*)&Kc[off], s1, 0, 0, 0);
            }
            sc[c] = s1;
        }
        __builtin_amdgcn_s_setprio(0);

        // --- masks: diagonal tile / window-edge zone (first 2 tiles, qb>=16)
        const bool dz = (t == tend);
        const bool wz = (qb >= 16) && (t <= tbeg + 1);
        if (dz) {
#pragma unroll
            for (int c = 0; c < 4; ++c) {
                int j = kv0 + c * 16 + l15;
#pragma unroll
                for (int r = 0; r < 4; ++r) {
                    int i = q0 + g * 16 + l4 * 4 + r;
                    if (j > i) sc[c][r] = -1e30f;
                }
            }
        } else if (wz) {
#pragma unroll
            for (int c = 0; c < 4; ++c) {
                int j = kv0 + c * 16 + l15;
#pragma unroll
                for (int r = 0; r < 4; ++r) {
                    int i = q0 + g * 16 + l4 * 4 + r;
                    if (i - j >= WIN_SZ) sc[c][r] = -1e30f;
                }
            }
        }

        // --- row max + defer-max rescale
        float rmax[4];
#pragma unroll
        for (int r = 0; r < 4; ++r)
            rmax[r] = fmaxf(fmaxf(sc[0][r], sc[1][r]), fmaxf(sc[2][r], sc[3][r]));
#pragma unroll
        for (int msk = 1; msk < 16; msk <<= 1)
#pragma unroll
            for (int r = 0; r < 4; ++r)
                rmax[r] = fmaxf(rmax[r], __shfl_xor(rmax[r], msk));
        bool need = false;
#pragma unroll
        for (int r = 0; r < 4; ++r)
            need = need || (rmax[r] > m[r] + 32.0f);
        if (__any(need)) {
            float fr[4];
#pragma unroll
            for (int r = 0; r < 4; ++r) {
                float nm = fmaxf(m[r], rmax[r]);
                fr[r] = __expf((m[r] - nm) * SCALE_F);
                m[r] = nm;
                l[r] *= fr[r];
            }
#pragma unroll
            for (int f = 0; f < 8; ++f)
#pragma unroll
                for (int r = 0; r < 4; ++r) {
                    aV1[f][r] *= fr[r];
                    aV2[f][r] *= fr[r];
                }
        }

        // --- P = exp((s-m)*SCALE); rowsum; P -> wave-private LDS (swizzled)
        float rs[4] = {0.f, 0.f, 0.f, 0.f};
#pragma unroll
        for (int c = 0; c < 4; ++c) {
            int col = c * 16 + l15;
#pragma unroll
            for (int r = 0; r < 4; ++r) {
                int prow = l4 * 4 + r;
                float p = __expf((sc[c][r] - m[r]) * SCALE_F);
                if (wz && (m[r] < -1e29f)) p = 0.f;   // fully-masked row
                rs[r] += p;
                int pco = ((col >> 3) ^ (prow & 7)) * 8 + (col & 7);
                Pw[prow * 64 + pco] = f2bf(p);
            }
        }
#pragma unroll
        for (int msk = 1; msk < 16; msk <<= 1)
#pragma unroll
            for (int r = 0; r < 4; ++r)
                rs[r] += __shfl_xor(rs[r], msk);
#pragma unroll
        for (int r = 0; r < 4; ++r) l[r] += rs[r];

        // --- PV vs both V halves (P read once per kk, reused)
        const u16* V0 = VBUF(cb, 0);
        const u16* V1 = VBUF(cb, 1);
        __builtin_amdgcn_s_setprio(1);
#pragma unroll
        for (int kk = 0; kk < 2; ++kk) {
            int pch = ((kk * 4 + l4) ^ (l15 & 7)) * 8;
            bf16x8 pa = *(const bf16x8*)&Pw[l15 * 64 + pch];
#pragma unroll
            for (int f = 0; f < 8; ++f) {
                int off = (f * 16 + l15) * 64 + (((kk * 4 + l4) ^ (l15 & 7)) * 8);
                aV1[f] = __builtin_amdgcn_mfma_f32_16x16x32_bf16(pa, *(const bf16x8*)&V0[off], aV1[f], 0, 0, 0);
                aV2[f] = __builtin_amdgcn_mfma_f32_16x16x32_bf16(pa, *(const bf16x8*)&V1[off], aV2[f], 0, 0, 0);
            }
        }
        __builtin_amdgcn_s_setprio(0);

        // --- single sync point per tile
        asm volatile("s_waitcnt vmcnt(0)" ::: "memory");
        __builtin_amdgcn_s_barrier();
        asm volatile("" ::: "memory");
        cb ^= 1;
    }

    // lambda scalar (all waves)
    float s1v = lq1[lane] * lk1[lane] + lq1[lane + 64] * lk1[lane + 64];
    float s2v = lq2[lane] * lk2[lane] + lq2[lane + 64] * lk2[lane + 64];
#pragma unroll
    for (int msk = 1; msk < 64; msk <<= 1) {
        s1v += __shfl_xor(s1v, msk);
        s2v += __shfl_xor(s2v, msk);
    }
    const float lam = __expf(s1v) - __expf(s2v) + LAMBDA_INIT_F;

    // cross-stream combine via f32 LDS overlay (stride 264 -> conflict-free)
    float* const Cmb = (float*)smem;
    if (sid == 1) {
#pragma unroll
        for (int r = 0; r < 4; ++r) {
            float inv2 = lam / l[r];
            int row = g * 16 + l4 * 4 + r;
#pragma unroll
            for (int f = 0; f < 8; ++f) {
                Cmb[row * 264 + f * 16 + l15]       = aV1[f][r] * inv2;
                Cmb[row * 264 + 128 + f * 16 + l15] = aV2[f][r] * inv2;
            }
        }
    }
    __syncthreads();
    if (sid == 0) {
        float sw0[8], sw1[8];
#pragma unroll
        for (int f = 0; f < 8; ++f) {
            sw0[f] = subln[f * 16 + l15];
            sw1[f] = subln[128 + f * 16 + l15];
        }
#pragma unroll
        for (int r = 0; r < 4; ++r) {
            float inv1 = 1.0f / l[r];
            int row = g * 16 + l4 * 4 + r;
            float o0[8], o1[8];
            float ssq = 0.f;
#pragma unroll
            for (int f = 0; f < 8; ++f) {
                o0[f] = aV1[f][r] * inv1 - Cmb[row * 264 + f * 16 + l15];
                o1[f] = aV2[f][r] * inv1 - Cmb[row * 264 + 128 + f * 16 + l15];
                ssq += o0[f] * o0[f] + o1[f] * o1[f];
            }
#pragma unroll
            for (int msk = 1; msk < 16; msk <<= 1) ssq += __shfl_xor(ssq, msk);
            float scale = rsqrtf(ssq * (1.0f / 256.0f) + 1e-5f) * ONE_MINUS_LI_F;
            u16* op = attnb + (size_t)(q0 + row) * 4096 + h * 256;
#pragma unroll
            for (int f = 0; f < 8; ++f) {
                op[f * 16 + l15]       = f2bf(o0[f] * scale * sw0[f]);
                op[128 + f * 16 + l15] = f2bf(o1[f] * scale * sw1[f]);
            }
        }
    }
#undef STAGE_TILE
#undef KBUF
#undef VBUF
}

// ---------------------------------------------------------------------------
extern "C" void kernel_launch(void* const* d_in, const int* in_sizes, int n_in,
                              void* d_out, int out_size, void* d_ws, size_t ws_size,
                              hipStream_t stream) {
    const float* hidden    = (const float*)d_in[0];
    const int*   positions = (const int*)d_in[1];
    const float* Wqkv_w    = (const float*)d_in[2];
    const float* Wqkv_b    = (const float*)d_in[3];
    const float* out_w     = (const float*)d_in[4];
    const float* out_b     = (const float*)d_in[5];
    const float* lq1       = (const float*)d_in[6];
    const float* lk1       = (const float*)d_in[7];
    const float* lq2       = (const float*)d_in[8];
    const float* lk2       = (const float*)d_in[9];
    const float* subln     = (const float*)d_in[10];
    float* out = (float*)d_out;

    u16* ws0   = (u16*)d_ws;
    u16* hb    = ws0;
    u16* wqb   = ws0 + 8388608;
    u16* qkvb  = ws0 + 33554432;
    u16* attnb = ws0;
    u16* owb   = ws0 + 8388608;
    u16* vt    = ws0 + 25165824;

    conv_f32_bf16<<<2048, 256, 0, stream>>>(hidden, hb, 2048 * 4096 / 4);
    conv_f32_bf16<<<2048, 256, 0, stream>>>(Wqkv_w, wqb, 6144 * 4096 / 4);

    // QKV: M=2048, N=6144, BN=192 -> 8 x 32 = 256 blocks
    gemm8p<3, 1><<<256, 512, 0, stream>>>(hb, wqb, Wqkv_b, qkvb, 2048, 6144, 4096, 32);

    rope_bf16<<<S_LEN, 256, 0, stream>>>(qkvb, positions);
    vtrans<<<dim3(32, 8), 256, 0, stream>>>(qkvb, vt);

    conv_f32_bf16<<<2048, 256, 0, stream>>>(out_w, owb, 4096 * 4096 / 4);

    // attention: 512 blocks (32 qb x 16 h, heavy-first remap), 8 waves
    attn_bf16<<<512, 512, 0, stream>>>(qkvb, vt, attnb, lq1, lk1, lq2, lk2, subln);

    // out: M=2048, N=4096, BN=128 -> 8 x 32 = 256 blocks
    gemm8p<2, 0><<<256, 512, 0, stream>>>(attnb, owb, out_b, out, 2048, 4096, 4096, 32);
}